// Round 1
// baseline (396.209 us; speedup 1.0000x reference)
//
#include <hip/hip_runtime.h>
#include <math.h>

// DeepOHeat_ST: 4 trunk MLPs + branch MLP, then rank-64 CP outer-product
// reconstruction out[b,i,j,k,l] = sum_z t0[i,z] t1[j,z] t2[k,z] t3[l,z] br[b,z]
//
// ws layout (floats):
//   t0T [z][i]  (64x64)  @ 0
//   t1T [z][j]  (64x64)  @ 4096
//   t2T [z][k]  (64x64)  @ 8192
//   t3T [z][l]  (64x32)  @ 12288
//   brT [z][b]  (64x8)   @ 14336
// total 14848 floats = 59392 bytes

#define HID 256
#define NFF 64

__global__ __launch_bounds__(256) void net_eval(
    const float* __restrict__ x1, const float* __restrict__ x2,
    const float* __restrict__ x3, const float* __restrict__ x4,
    const float* __restrict__ f,  const float* __restrict__ Bm,
    const float* __restrict__ tW0, const float* __restrict__ tb0,
    const float* __restrict__ tW1, const float* __restrict__ tb1,
    const float* __restrict__ tW2, const float* __restrict__ tb2,
    const float* __restrict__ tW3, const float* __restrict__ tb3,
    const float* __restrict__ bW0, const float* __restrict__ bb0,
    const float* __restrict__ bW1, const float* __restrict__ bb1,
    const float* __restrict__ bW2, const float* __restrict__ bb2,
    const float* __restrict__ bW3, const float* __restrict__ bb3,
    float* __restrict__ ws)
{
    __shared__ float bufA[HID];
    __shared__ float bufB[HID];
    const int t = threadIdx.x;
    const int bid = blockIdx.x;

    int net, row;
    if (bid < 192)      { net = bid >> 6; row = bid & 63; }
    else if (bid < 224) { net = 3;        row = bid - 192; }
    else                { net = 4;        row = bid - 224; }

    const float *W0, *B0v, *W1, *B1v, *W2, *B2v, *W3, *B3v;
    int in0;
    if (net < 4) {
        W0 = tW0 + (size_t)net * HID * 2 * NFF; B0v = tb0 + net * HID;
        W1 = tW1 + (size_t)net * HID * HID;     B1v = tb1 + net * HID;
        W2 = tW2 + (size_t)net * HID * HID;     B2v = tb2 + net * HID;
        W3 = tW3 + (size_t)net * 64 * HID;      B3v = tb3 + net * 64;
        in0 = 2 * NFF;
        const float* xp = (net == 0) ? x1 : (net == 1) ? x2 : (net == 2) ? x3 : x4;
        float xv = xp[row];
        if (t < 128) {
            float p = xv * Bm[t & 63];
            bufA[t] = (t < 64) ? cosf(p) : sinf(p);
        }
    } else {
        W0 = bW0; B0v = bb0; W1 = bW1; B1v = bb1;
        W2 = bW2; B2v = bb2; W3 = bW3; B3v = bb3;
        in0 = 256;
        bufA[t] = f[(size_t)row * 256 + t];
    }
    __syncthreads();

    // L0: bufA(in0) -> bufB  (swish). 4 independent partial accumulators to
    // break the serial FMA dependency chain (we run at ~1 wave/SIMD here).
    {
        const float4* wr = (const float4*)(W0 + (size_t)t * in0);
        const float4* iv = (const float4*)bufA;
        const int n4 = in0 >> 2;
        float4 a4 = make_float4(0.f, 0.f, 0.f, 0.f);
        for (int k = 0; k < n4; ++k) {
            float4 w = wr[k]; float4 v = iv[k];
            a4.x += w.x * v.x; a4.y += w.y * v.y;
            a4.z += w.z * v.z; a4.w += w.w * v.w;
        }
        float acc = B0v[t] + ((a4.x + a4.y) + (a4.z + a4.w));
        bufB[t] = acc / (1.0f + expf(-acc));
    }
    __syncthreads();

    // L1: bufB(256) -> bufA  (swish)
    {
        const float4* wr = (const float4*)(W1 + (size_t)t * HID);
        const float4* iv = (const float4*)bufB;
        float4 a4 = make_float4(0.f, 0.f, 0.f, 0.f);
        for (int k = 0; k < HID / 4; ++k) {
            float4 w = wr[k]; float4 v = iv[k];
            a4.x += w.x * v.x; a4.y += w.y * v.y;
            a4.z += w.z * v.z; a4.w += w.w * v.w;
        }
        float acc = B1v[t] + ((a4.x + a4.y) + (a4.z + a4.w));
        bufA[t] = acc / (1.0f + expf(-acc));
    }
    __syncthreads();

    // L2: bufA(256) -> bufB  (swish)
    {
        const float4* wr = (const float4*)(W2 + (size_t)t * HID);
        const float4* iv = (const float4*)bufA;
        float4 a4 = make_float4(0.f, 0.f, 0.f, 0.f);
        for (int k = 0; k < HID / 4; ++k) {
            float4 w = wr[k]; float4 v = iv[k];
            a4.x += w.x * v.x; a4.y += w.y * v.y;
            a4.z += w.z * v.z; a4.w += w.w * v.w;
        }
        float acc = B2v[t] + ((a4.x + a4.y) + (a4.z + a4.w));
        bufB[t] = acc / (1.0f + expf(-acc));
    }
    __syncthreads();

    // L3: bufB(256) -> 64 outputs, stored transposed into ws
    if (t < 64) {
        const float4* wr = (const float4*)(W3 + (size_t)t * HID);
        const float4* iv = (const float4*)bufB;
        float4 a4 = make_float4(0.f, 0.f, 0.f, 0.f);
        for (int k = 0; k < HID / 4; ++k) {
            float4 w = wr[k]; float4 v = iv[k];
            a4.x += w.x * v.x; a4.y += w.y * v.y;
            a4.z += w.z * v.z; a4.w += w.w * v.w;
        }
        float acc = B3v[t] + ((a4.x + a4.y) + (a4.z + a4.w));
        int base, stride;
        if      (net == 0) { base = 0;     stride = 64; }
        else if (net == 1) { base = 4096;  stride = 64; }
        else if (net == 2) { base = 8192;  stride = 64; }
        else if (net == 3) { base = 12288; stride = 32; }
        else               { base = 14336; stride = 8;  }
        ws[base + t * stride + row] = acc;
    }
}

// CP reconstruction, v2: amortize LDS reads over 4 j-planes per thread.
// t2/t3 are block-invariant; only s[z] = t0[i,z]*t1[j,z]*br[b,z] depends on
// (b,i,j). Each thread now owns a 4j x 8k x 4l register tile (128 acc VGPRs),
// so per z-iter a wave issues only 2x b128 (t2) + 1x b128 (t3) + 1x b128
// broadcast (4 s-values, z-major layout -> single address for the wave)
// for 128 FMAs -> LDS demand ~36 us/CU, under the 61 us VALU floor.
//
// Grid: 2048 blocks = b(8) x i(64) x jtile(4). Block: 256 threads = 4 waves;
// wave jj handles j = j0 + jj*4 + {0..3}.
__global__ __launch_bounds__(256) void cp_recon(
    const float* __restrict__ ws, float* __restrict__ out)
{
    __shared__ float t2s[64 * 64];  // [z][k]
    __shared__ float t3s[64 * 32];  // [z][l]
    __shared__ float sS[64 * 16];   // [z][jq]  z-major: wave reads 1 float4

    const int t = threadIdx.x;
    const int bid = blockIdx.x;
    const int b  = bid >> 8;
    const int i  = (bid >> 2) & 63;
    const int j0 = (bid & 3) * 16;

    // stage t2T, t3T (straight copy: coalesced global, conflict-free LDS)
    #pragma unroll
    for (int m = 0; m < 16; ++m) {
        int g = t + m * 256;
        t2s[g] = ws[8192 + g];
    }
    #pragma unroll
    for (int m = 0; m < 8; ++m) {
        int g = t + m * 256;
        t3s[g] = ws[12288 + g];
    }
    // sS[z][jq] = t0[i,z] * t1[j0+jq,z] * br[b,z]   (jq = 0..15)
    {
        const int jq = t & 15;
        const int zb = t >> 4;
        #pragma unroll
        for (int q = 0; q < 4; ++q) {
            int z = zb + q * 16;
            sS[z * 16 + jq] =
                ws[z * 64 + i] * ws[4096 + z * 64 + j0 + jq] * ws[14336 + z * 8 + b];
        }
    }
    __syncthreads();

    const int jj   = t >> 6;          // wave index -> j group
    const int lane = t & 63;
    const int k0   = (lane >> 3) * 8;
    const int l0   = (lane & 7) * 4;

    float4 acc[4][8];                 // [jl][kk] -> 128 VGPRs
    #pragma unroll
    for (int jl = 0; jl < 4; ++jl)
        #pragma unroll
        for (int kk = 0; kk < 8; ++kk)
            acc[jl][kk] = make_float4(0.f, 0.f, 0.f, 0.f);

    for (int z = 0; z < 64; ++z) {
        float4 a0  = *(const float4*)&t2s[z * 64 + k0];
        float4 a1  = *(const float4*)&t2s[z * 64 + k0 + 4];
        float4 t3v = *(const float4*)&t3s[z * 32 + l0];
        float4 s4  = *(const float4*)&sS[z * 16 + jj * 4];  // broadcast read
        const float ks0 = a0.x, ks1 = a0.y, ks2 = a0.z, ks3 = a0.w;
        const float ks4 = a1.x, ks5 = a1.y, ks6 = a1.z, ks7 = a1.w;
        #pragma unroll
        for (int jl = 0; jl < 4; ++jl) {
            const float sz = (jl == 0) ? s4.x : (jl == 1) ? s4.y
                           : (jl == 2) ? s4.z : s4.w;
            float4 u;
            u.x = sz * t3v.x; u.y = sz * t3v.y; u.z = sz * t3v.z; u.w = sz * t3v.w;
            acc[jl][0].x += ks0 * u.x; acc[jl][0].y += ks0 * u.y; acc[jl][0].z += ks0 * u.z; acc[jl][0].w += ks0 * u.w;
            acc[jl][1].x += ks1 * u.x; acc[jl][1].y += ks1 * u.y; acc[jl][1].z += ks1 * u.z; acc[jl][1].w += ks1 * u.w;
            acc[jl][2].x += ks2 * u.x; acc[jl][2].y += ks2 * u.y; acc[jl][2].z += ks2 * u.z; acc[jl][2].w += ks2 * u.w;
            acc[jl][3].x += ks3 * u.x; acc[jl][3].y += ks3 * u.y; acc[jl][3].z += ks3 * u.z; acc[jl][3].w += ks3 * u.w;
            acc[jl][4].x += ks4 * u.x; acc[jl][4].y += ks4 * u.y; acc[jl][4].z += ks4 * u.z; acc[jl][4].w += ks4 * u.w;
            acc[jl][5].x += ks5 * u.x; acc[jl][5].y += ks5 * u.y; acc[jl][5].z += ks5 * u.z; acc[jl][5].w += ks5 * u.w;
            acc[jl][6].x += ks6 * u.x; acc[jl][6].y += ks6 * u.y; acc[jl][6].z += ks6 * u.z; acc[jl][6].w += ks6 * u.w;
            acc[jl][7].x += ks7 * u.x; acc[jl][7].y += ks7 * u.y; acc[jl][7].z += ks7 * u.z; acc[jl][7].w += ks7 * u.w;
        }
    }

    // out[b][i][j][k][l], plane (k,l) = 2048 floats, contiguous
    #pragma unroll
    for (int jl = 0; jl < 4; ++jl) {
        const int j = j0 + jj * 4 + jl;
        size_t base = ((size_t)((b * 64 + i) * 64 + j)) * 2048;
        float* op = out + base;
        #pragma unroll
        for (int kk = 0; kk < 8; ++kk) {
            *(float4*)&op[(k0 + kk) * 32 + l0] = acc[jl][kk];
        }
    }
}

extern "C" void kernel_launch(void* const* d_in, const int* in_sizes, int n_in,
                              void* d_out, int out_size, void* d_ws, size_t ws_size,
                              hipStream_t stream) {
    const float* x1  = (const float*)d_in[0];
    const float* x2  = (const float*)d_in[1];
    const float* x3  = (const float*)d_in[2];
    const float* x4  = (const float*)d_in[3];
    const float* f   = (const float*)d_in[4];
    const float* Bm  = (const float*)d_in[5];
    const float* tW0 = (const float*)d_in[6];
    const float* tb0 = (const float*)d_in[7];
    const float* tW1 = (const float*)d_in[8];
    const float* tb1 = (const float*)d_in[9];
    const float* tW2 = (const float*)d_in[10];
    const float* tb2 = (const float*)d_in[11];
    const float* tW3 = (const float*)d_in[12];
    const float* tb3 = (const float*)d_in[13];
    const float* bW0 = (const float*)d_in[14];
    const float* bb0 = (const float*)d_in[15];
    const float* bW1 = (const float*)d_in[16];
    const float* bb1 = (const float*)d_in[17];
    const float* bW2 = (const float*)d_in[18];
    const float* bb2 = (const float*)d_in[19];
    const float* bW3 = (const float*)d_in[20];
    const float* bb3 = (const float*)d_in[21];

    float* ws  = (float*)d_ws;
    float* out = (float*)d_out;

    hipLaunchKernelGGL(net_eval, dim3(232), dim3(256), 0, stream,
                       x1, x2, x3, x4, f, Bm,
                       tW0, tb0, tW1, tb1, tW2, tb2, tW3, tb3,
                       bW0, bb0, bW1, bb1, bW2, bb2, bW3, bb3, ws);
    hipLaunchKernelGGL(cp_recon, dim3(2048), dim3(256), 0, stream, ws, out);
}

// Round 2
// 394.407 us; speedup vs baseline: 1.0046x; 1.0046x over previous
//
#include <hip/hip_runtime.h>
#include <math.h>

// DeepOHeat_ST: 4 trunk MLPs + branch MLP, then rank-64 CP outer-product
// reconstruction out[b,i,j,k,l] = sum_z t0[i,z] t1[j,z] t2[k,z] t3[l,z] br[b,z]
//
// *** DIAGNOSTIC ROUND ***: cp_recon folded to grid=512 (4x serial j-tiles
// per block, identical math + identical total FMA count) so its dispatch
// duration exceeds the 167us poison-fill cutoff and becomes visible in the
// rocprof top-5. This measures cp_recon's true per-j-tile cost:
//     cp_old ~= D_cp/4 + staging
// and whether dur_us tracks kernel time 1:1 (via dur delta vs 3/4*D_cp).
//
// ws layout (floats):
//   t0T [z][i]  (64x64)  @ 0
//   t1T [z][j]  (64x64)  @ 4096
//   t2T [z][k]  (64x64)  @ 8192
//   t3T [z][l]  (64x32)  @ 12288
//   brT [z][b]  (64x8)   @ 14336

#define HID 256
#define NFF 64

__global__ __launch_bounds__(256) void net_eval(
    const float* __restrict__ x1, const float* __restrict__ x2,
    const float* __restrict__ x3, const float* __restrict__ x4,
    const float* __restrict__ f,  const float* __restrict__ Bm,
    const float* __restrict__ tW0, const float* __restrict__ tb0,
    const float* __restrict__ tW1, const float* __restrict__ tb1,
    const float* __restrict__ tW2, const float* __restrict__ tb2,
    const float* __restrict__ tW3, const float* __restrict__ tb3,
    const float* __restrict__ bW0, const float* __restrict__ bb0,
    const float* __restrict__ bW1, const float* __restrict__ bb1,
    const float* __restrict__ bW2, const float* __restrict__ bb2,
    const float* __restrict__ bW3, const float* __restrict__ bb3,
    float* __restrict__ ws)
{
    __shared__ float bufA[HID];
    __shared__ float bufB[HID];
    const int t = threadIdx.x;
    const int bid = blockIdx.x;

    int net, row;
    if (bid < 192)      { net = bid >> 6; row = bid & 63; }
    else if (bid < 224) { net = 3;        row = bid - 192; }
    else                { net = 4;        row = bid - 224; }

    const float *W0, *B0v, *W1, *B1v, *W2, *B2v, *W3, *B3v;
    int in0;
    if (net < 4) {
        W0 = tW0 + (size_t)net * HID * 2 * NFF; B0v = tb0 + net * HID;
        W1 = tW1 + (size_t)net * HID * HID;     B1v = tb1 + net * HID;
        W2 = tW2 + (size_t)net * HID * HID;     B2v = tb2 + net * HID;
        W3 = tW3 + (size_t)net * 64 * HID;      B3v = tb3 + net * 64;
        in0 = 2 * NFF;
        const float* xp = (net == 0) ? x1 : (net == 1) ? x2 : (net == 2) ? x3 : x4;
        float xv = xp[row];
        if (t < 128) {
            float p = xv * Bm[t & 63];
            bufA[t] = (t < 64) ? cosf(p) : sinf(p);
        }
    } else {
        W0 = bW0; B0v = bb0; W1 = bW1; B1v = bb1;
        W2 = bW2; B2v = bb2; W3 = bW3; B3v = bb3;
        in0 = 256;
        bufA[t] = f[(size_t)row * 256 + t];
    }
    __syncthreads();

    // L0
    {
        const float4* wr = (const float4*)(W0 + (size_t)t * in0);
        const float4* iv = (const float4*)bufA;
        const int n4 = in0 >> 2;
        float4 a4 = make_float4(0.f, 0.f, 0.f, 0.f);
        for (int k = 0; k < n4; ++k) {
            float4 w = wr[k]; float4 v = iv[k];
            a4.x += w.x * v.x; a4.y += w.y * v.y;
            a4.z += w.z * v.z; a4.w += w.w * v.w;
        }
        float acc = B0v[t] + ((a4.x + a4.y) + (a4.z + a4.w));
        bufB[t] = acc / (1.0f + expf(-acc));
    }
    __syncthreads();

    // L1
    {
        const float4* wr = (const float4*)(W1 + (size_t)t * HID);
        const float4* iv = (const float4*)bufB;
        float4 a4 = make_float4(0.f, 0.f, 0.f, 0.f);
        for (int k = 0; k < HID / 4; ++k) {
            float4 w = wr[k]; float4 v = iv[k];
            a4.x += w.x * v.x; a4.y += w.y * v.y;
            a4.z += w.z * v.z; a4.w += w.w * v.w;
        }
        float acc = B1v[t] + ((a4.x + a4.y) + (a4.z + a4.w));
        bufA[t] = acc / (1.0f + expf(-acc));
    }
    __syncthreads();

    // L2
    {
        const float4* wr = (const float4*)(W2 + (size_t)t * HID);
        const float4* iv = (const float4*)bufA;
        float4 a4 = make_float4(0.f, 0.f, 0.f, 0.f);
        for (int k = 0; k < HID / 4; ++k) {
            float4 w = wr[k]; float4 v = iv[k];
            a4.x += w.x * v.x; a4.y += w.y * v.y;
            a4.z += w.z * v.z; a4.w += w.w * v.w;
        }
        float acc = B2v[t] + ((a4.x + a4.y) + (a4.z + a4.w));
        bufB[t] = acc / (1.0f + expf(-acc));
    }
    __syncthreads();

    // L3 -> transposed into ws
    if (t < 64) {
        const float4* wr = (const float4*)(W3 + (size_t)t * HID);
        const float4* iv = (const float4*)bufB;
        float4 a4 = make_float4(0.f, 0.f, 0.f, 0.f);
        for (int k = 0; k < HID / 4; ++k) {
            float4 w = wr[k]; float4 v = iv[k];
            a4.x += w.x * v.x; a4.y += w.y * v.y;
            a4.z += w.z * v.z; a4.w += w.w * v.w;
        }
        float acc = B3v[t] + ((a4.x + a4.y) + (a4.z + a4.w));
        int base, stride;
        if      (net == 0) { base = 0;     stride = 64; }
        else if (net == 1) { base = 4096;  stride = 64; }
        else if (net == 2) { base = 8192;  stride = 64; }
        else if (net == 3) { base = 12288; stride = 32; }
        else               { base = 14336; stride = 8;  }
        ws[base + t * stride + row] = acc;
    }
}

// CP reconstruction, diagnostic fold: grid 512 = b(8) x i(64). Each block
// serially processes all 4 j-tiles (j0 = 0,16,32,48) with the same per-tile
// inner loop as round-1. Total FMAs identical; staging amortized 4x.
__global__ __launch_bounds__(256) void cp_recon(
    const float* __restrict__ ws, float* __restrict__ out)
{
    __shared__ float t2s[64 * 64];  // [z][k]   16 KB
    __shared__ float t3s[64 * 32];  // [z][l]    8 KB
    __shared__ float sS[64 * 64];   // [z][j]   16 KB  (all 64 j for this (b,i))

    const int t = threadIdx.x;
    const int bid = blockIdx.x;
    const int b = bid >> 6;
    const int i = bid & 63;

    // stage t2T, t3T via float4 (coalesced, conflict-free)
    {
        const float4* ws4 = (const float4*)ws;
        float4* t2s4 = (float4*)t2s;
        float4* t3s4 = (float4*)t3s;
        #pragma unroll
        for (int m = 0; m < 4; ++m) t2s4[t + m * 256] = ws4[2048 + t + m * 256];
        #pragma unroll
        for (int m = 0; m < 2; ++m) t3s4[t + m * 256] = ws4[3072 + t + m * 256];
    }
    // sS[z][j] = t0[i,z] * t1[j,z] * br[b,z]  (all 64 j)
    {
        const int j  = t & 63;
        const int zb = t >> 6;   // 0..3
        #pragma unroll
        for (int q = 0; q < 16; ++q) {
            int z = zb * 16 + q;
            sS[z * 64 + j] =
                ws[z * 64 + i] * ws[4096 + z * 64 + j] * ws[14336 + z * 8 + b];
        }
    }
    __syncthreads();

    const int jj   = t >> 6;          // wave index
    const int lane = t & 63;
    const int k0   = (lane >> 3) * 8;
    const int l0   = (lane & 7) * 4;

    #pragma unroll 1
    for (int jt = 0; jt < 4; ++jt) {
        const int j0 = jt * 16;

        float4 acc[4][8];
        #pragma unroll
        for (int jl = 0; jl < 4; ++jl)
            #pragma unroll
            for (int kk = 0; kk < 8; ++kk)
                acc[jl][kk] = make_float4(0.f, 0.f, 0.f, 0.f);

        #pragma unroll 4
        for (int z = 0; z < 64; ++z) {
            float4 a0  = *(const float4*)&t2s[z * 64 + k0];
            float4 a1  = *(const float4*)&t2s[z * 64 + k0 + 4];
            float4 t3v = *(const float4*)&t3s[z * 32 + l0];
            float4 s4  = *(const float4*)&sS[z * 64 + j0 + jj * 4];  // broadcast
            const float ks0 = a0.x, ks1 = a0.y, ks2 = a0.z, ks3 = a0.w;
            const float ks4 = a1.x, ks5 = a1.y, ks6 = a1.z, ks7 = a1.w;
            #pragma unroll
            for (int jl = 0; jl < 4; ++jl) {
                const float sz = (jl == 0) ? s4.x : (jl == 1) ? s4.y
                               : (jl == 2) ? s4.z : s4.w;
                float4 u;
                u.x = sz * t3v.x; u.y = sz * t3v.y; u.z = sz * t3v.z; u.w = sz * t3v.w;
                acc[jl][0].x += ks0 * u.x; acc[jl][0].y += ks0 * u.y; acc[jl][0].z += ks0 * u.z; acc[jl][0].w += ks0 * u.w;
                acc[jl][1].x += ks1 * u.x; acc[jl][1].y += ks1 * u.y; acc[jl][1].z += ks1 * u.z; acc[jl][1].w += ks1 * u.w;
                acc[jl][2].x += ks2 * u.x; acc[jl][2].y += ks2 * u.y; acc[jl][2].z += ks2 * u.z; acc[jl][2].w += ks2 * u.w;
                acc[jl][3].x += ks3 * u.x; acc[jl][3].y += ks3 * u.y; acc[jl][3].z += ks3 * u.z; acc[jl][3].w += ks3 * u.w;
                acc[jl][4].x += ks4 * u.x; acc[jl][4].y += ks4 * u.y; acc[jl][4].z += ks4 * u.z; acc[jl][4].w += ks4 * u.w;
                acc[jl][5].x += ks5 * u.x; acc[jl][5].y += ks5 * u.y; acc[jl][5].z += ks5 * u.z; acc[jl][5].w += ks5 * u.w;
                acc[jl][6].x += ks6 * u.x; acc[jl][6].y += ks6 * u.y; acc[jl][6].z += ks6 * u.z; acc[jl][6].w += ks6 * u.w;
                acc[jl][7].x += ks7 * u.x; acc[jl][7].y += ks7 * u.y; acc[jl][7].z += ks7 * u.z; acc[jl][7].w += ks7 * u.w;
            }
        }

        // out[b][i][j][k][l], plane (k,l) = 2048 floats
        #pragma unroll
        for (int jl = 0; jl < 4; ++jl) {
            const int j = j0 + jj * 4 + jl;
            size_t base = ((size_t)((b * 64 + i) * 64 + j)) * 2048;
            float* op = out + base;
            #pragma unroll
            for (int kk = 0; kk < 8; ++kk) {
                *(float4*)&op[(k0 + kk) * 32 + l0] = acc[jl][kk];
            }
        }
    }
}

extern "C" void kernel_launch(void* const* d_in, const int* in_sizes, int n_in,
                              void* d_out, int out_size, void* d_ws, size_t ws_size,
                              hipStream_t stream) {
    const float* x1  = (const float*)d_in[0];
    const float* x2  = (const float*)d_in[1];
    const float* x3  = (const float*)d_in[2];
    const float* x4  = (const float*)d_in[3];
    const float* f   = (const float*)d_in[4];
    const float* Bm  = (const float*)d_in[5];
    const float* tW0 = (const float*)d_in[6];
    const float* tb0 = (const float*)d_in[7];
    const float* tW1 = (const float*)d_in[8];
    const float* tb1 = (const float*)d_in[9];
    const float* tW2 = (const float*)d_in[10];
    const float* tb2 = (const float*)d_in[11];
    const float* tW3 = (const float*)d_in[12];
    const float* tb3 = (const float*)d_in[13];
    const float* bW0 = (const float*)d_in[14];
    const float* bb0 = (const float*)d_in[15];
    const float* bW1 = (const float*)d_in[16];
    const float* bb1 = (const float*)d_in[17];
    const float* bW2 = (const float*)d_in[18];
    const float* bb2 = (const float*)d_in[19];
    const float* bW3 = (const float*)d_in[20];
    const float* bb3 = (const float*)d_in[21];

    float* ws  = (float*)d_ws;
    float* out = (float*)d_out;

    hipLaunchKernelGGL(net_eval, dim3(232), dim3(256), 0, stream,
                       x1, x2, x3, x4, f, Bm,
                       tW0, tb0, tW1, tb1, tW2, tb2, tW3, tb3,
                       bW0, bb0, bW1, bb1, bW2, bb2, bW3, bb3, ws);
    hipLaunchKernelGGL(cp_recon, dim3(512), dim3(256), 0, stream, ws, out);
}

// Round 4
// 362.075 us; speedup vs baseline: 1.0943x; 1.0893x over previous
//
#include <hip/hip_runtime.h>
#include <math.h>

// DeepOHeat_ST: 4 trunk MLPs + branch MLP, then rank-64 CP reconstruction
// out[b,i,j,k,l] = sum_z t0[i,z] t1[j,z] t2[k,z] t3[l,z] br[b,z]
//
// cp_recon v3 (MFMA): per block (b,i), compute the 64(j) x 2048(kl) plane as
// S(64x64) @ T(64x2048) with T[z,kl] = t2[k,z]*t3[l,z], using
// mfma_f32_16x16x32_bf16 and a 3-product bf16 split (hi=RNE, mid=trunc):
//   S*T ~= S0T0 + S1T0 + S0T1   (error ~2^-17 relative)
// A and B fragments use the SAME k-mapping formula, so the MFMA dot product
// is correct under any consistent per-lane-group k permutation; only the
// C/D mapping (col=lane&15, row=(lane>>4)*4+reg) is relied on as HW truth.
//
// (Round 4 = identical resubmit of round 3: that bench died to a container
// acquire failure, which carries no information about the kernel.)
//
// ws layout (floats):
//   t0T [z][i]  (64x64)  @ 0
//   t1T [z][j]  (64x64)  @ 4096
//   t2T [z][k]  (64x64)  @ 8192
//   t3T [z][l]  (64x32)  @ 12288
//   brT [z][b]  (64x8)   @ 14336

#define HID 256
#define NFF 64

__global__ __launch_bounds__(256) void net_eval(
    const float* __restrict__ x1, const float* __restrict__ x2,
    const float* __restrict__ x3, const float* __restrict__ x4,
    const float* __restrict__ f,  const float* __restrict__ Bm,
    const float* __restrict__ tW0, const float* __restrict__ tb0,
    const float* __restrict__ tW1, const float* __restrict__ tb1,
    const float* __restrict__ tW2, const float* __restrict__ tb2,
    const float* __restrict__ tW3, const float* __restrict__ tb3,
    const float* __restrict__ bW0, const float* __restrict__ bb0,
    const float* __restrict__ bW1, const float* __restrict__ bb1,
    const float* __restrict__ bW2, const float* __restrict__ bb2,
    const float* __restrict__ bW3, const float* __restrict__ bb3,
    float* __restrict__ ws)
{
    __shared__ float bufA[HID];
    __shared__ float bufB[HID];
    const int t = threadIdx.x;
    const int bid = blockIdx.x;

    int net, row;
    if (bid < 192)      { net = bid >> 6; row = bid & 63; }
    else if (bid < 224) { net = 3;        row = bid - 192; }
    else                { net = 4;        row = bid - 224; }

    const float *W0, *B0v, *W1, *B1v, *W2, *B2v, *W3, *B3v;
    int in0;
    if (net < 4) {
        W0 = tW0 + (size_t)net * HID * 2 * NFF; B0v = tb0 + net * HID;
        W1 = tW1 + (size_t)net * HID * HID;     B1v = tb1 + net * HID;
        W2 = tW2 + (size_t)net * HID * HID;     B2v = tb2 + net * HID;
        W3 = tW3 + (size_t)net * 64 * HID;      B3v = tb3 + net * 64;
        in0 = 2 * NFF;
        const float* xp = (net == 0) ? x1 : (net == 1) ? x2 : (net == 2) ? x3 : x4;
        float xv = xp[row];
        if (t < 128) {
            float p = xv * Bm[t & 63];
            bufA[t] = (t < 64) ? cosf(p) : sinf(p);
        }
    } else {
        W0 = bW0; B0v = bb0; W1 = bW1; B1v = bb1;
        W2 = bW2; B2v = bb2; W3 = bW3; B3v = bb3;
        in0 = 256;
        bufA[t] = f[(size_t)row * 256 + t];
    }
    __syncthreads();

    // L0
    {
        const float4* wr = (const float4*)(W0 + (size_t)t * in0);
        const float4* iv = (const float4*)bufA;
        const int n4 = in0 >> 2;
        float4 a4 = make_float4(0.f, 0.f, 0.f, 0.f);
        for (int k = 0; k < n4; ++k) {
            float4 w = wr[k]; float4 v = iv[k];
            a4.x += w.x * v.x; a4.y += w.y * v.y;
            a4.z += w.z * v.z; a4.w += w.w * v.w;
        }
        float acc = B0v[t] + ((a4.x + a4.y) + (a4.z + a4.w));
        bufB[t] = acc / (1.0f + expf(-acc));
    }
    __syncthreads();

    // L1
    {
        const float4* wr = (const float4*)(W1 + (size_t)t * HID);
        const float4* iv = (const float4*)bufB;
        float4 a4 = make_float4(0.f, 0.f, 0.f, 0.f);
        for (int k = 0; k < HID / 4; ++k) {
            float4 w = wr[k]; float4 v = iv[k];
            a4.x += w.x * v.x; a4.y += w.y * v.y;
            a4.z += w.z * v.z; a4.w += w.w * v.w;
        }
        float acc = B1v[t] + ((a4.x + a4.y) + (a4.z + a4.w));
        bufA[t] = acc / (1.0f + expf(-acc));
    }
    __syncthreads();

    // L2
    {
        const float4* wr = (const float4*)(W2 + (size_t)t * HID);
        const float4* iv = (const float4*)bufA;
        float4 a4 = make_float4(0.f, 0.f, 0.f, 0.f);
        for (int k = 0; k < HID / 4; ++k) {
            float4 w = wr[k]; float4 v = iv[k];
            a4.x += w.x * v.x; a4.y += w.y * v.y;
            a4.z += w.z * v.z; a4.w += w.w * v.w;
        }
        float acc = B2v[t] + ((a4.x + a4.y) + (a4.z + a4.w));
        bufB[t] = acc / (1.0f + expf(-acc));
    }
    __syncthreads();

    // L3 -> transposed into ws
    if (t < 64) {
        const float4* wr = (const float4*)(W3 + (size_t)t * HID);
        const float4* iv = (const float4*)bufB;
        float4 a4 = make_float4(0.f, 0.f, 0.f, 0.f);
        for (int k = 0; k < HID / 4; ++k) {
            float4 w = wr[k]; float4 v = iv[k];
            a4.x += w.x * v.x; a4.y += w.y * v.y;
            a4.z += w.z * v.z; a4.w += w.w * v.w;
        }
        float acc = B3v[t] + ((a4.x + a4.y) + (a4.z + a4.w));
        int base, stride;
        if      (net == 0) { base = 0;     stride = 64; }
        else if (net == 1) { base = 4096;  stride = 64; }
        else if (net == 2) { base = 8192;  stride = 64; }
        else if (net == 3) { base = 12288; stride = 32; }
        else               { base = 14336; stride = 8;  }
        ws[base + t * stride + row] = acc;
    }
}

// ---------------- cp_recon v3: MFMA ----------------

#define PADZ 68   // f32 row stride for t2T2/t3T2 (64+4: 16B-aligned, 2-way banks)
#define PADS 72   // ushort row stride for sHi/sMid (64+8: 16B-aligned)

typedef __attribute__((ext_vector_type(8))) short bf16x8;
typedef __attribute__((ext_vector_type(4))) float f32x4;

// RNE round f32 -> bf16, returned as the f32 bit pattern with low 16 zeroed
__device__ __forceinline__ unsigned bf16_rne_bits(float x) {
    unsigned u = __float_as_uint(x);
    return (u + 0x7fffu + ((u >> 16) & 1u)) & 0xffff0000u;
}

__global__ __launch_bounds__(256) void cp_recon(
    const float* __restrict__ ws, float* __restrict__ out)
{
    __shared__ __attribute__((aligned(16))) float t2T2[64 * PADZ];          // [k][z]
    __shared__ __attribute__((aligned(16))) float t3T2[32 * PADZ];          // [lv][z]
    __shared__ __attribute__((aligned(16))) unsigned short sHi [64 * PADS]; // [j][z]
    __shared__ __attribute__((aligned(16))) unsigned short sMid[64 * PADS];

    const int t = threadIdx.x;
    const int bid = blockIdx.x;
    const int b = bid >> 6;
    const int i = bid & 63;

    // stage t2 transposed to [k][z], t3 to [lv][z]
    #pragma unroll
    for (int m = 0; m < 16; ++m) {
        int idx = t + m * 256;            // = z*64 + k
        int z = idx >> 6, k = idx & 63;
        t2T2[k * PADZ + z] = ws[8192 + idx];
    }
    #pragma unroll
    for (int m = 0; m < 8; ++m) {
        int idx = t + m * 256;            // = z*32 + lv
        int z = idx >> 5, lv = idx & 31;
        t3T2[lv * PADZ + z] = ws[12288 + idx];
    }
    // S[j,z] = t0[i,z]*t1[j,z]*br[b,z], split hi (RNE) + mid (trunc)
    {
        const int j  = t & 63;
        const int zb = t >> 6;
        #pragma unroll
        for (int q = 0; q < 16; ++q) {
            int z = zb * 16 + q;
            float s = ws[z * 64 + i] * ws[4096 + z * 64 + j] * ws[14336 + z * 8 + b];
            unsigned hb = bf16_rne_bits(s);
            float r = s - __uint_as_float(hb);
            sHi [j * PADS + z] = (unsigned short)(hb >> 16);
            sMid[j * PADS + z] = (unsigned short)(__float_as_uint(r) >> 16);
        }
    }
    __syncthreads();

    const int w    = t >> 6;
    const int lane = t & 63;
    const int lg   = lane >> 4;   // k-group within fragment
    const int lr   = lane & 15;   // M-row (A) / N-col (B) index

    // Preload A fragments: S rows, hi & mid, for 4 M-tiles x 2 K-steps.
    bf16x8 Ah[4][2], Amid[4][2];
    #pragma unroll
    for (int m = 0; m < 4; ++m) {
        #pragma unroll
        for (int kt = 0; kt < 2; ++kt) {
            int j = m * 16 + lr, z0 = kt * 32 + lg * 8;
            Ah[m][kt]   = *(const bf16x8*)&sHi [j * PADS + z0];
            Amid[m][kt] = *(const bf16x8*)&sMid[j * PADS + z0];
        }
    }
    // Preload this lane's t3 rows (both n-parities) into registers: the 16
    // z-values it will ever need. Avoids per-iteration 16-row bank conflicts.
    float t3r[2][2][8];
    #pragma unroll
    for (int par = 0; par < 2; ++par) {
        #pragma unroll
        for (int kt = 0; kt < 2; ++kt) {
            const float* p = &t3T2[(par * 16 + lr) * PADZ + kt * 32 + lg * 8];
            #pragma unroll
            for (int e = 0; e < 8; ++e) t3r[par][kt][e] = p[e];
        }
    }

    float* op = out + ((size_t)((b * 64 + i) * 64)) * 2048;  // j=0, col=0 base

    // Wave w owns cols [w*512, w*512+512) = N-tiles n in [w*32, w*32+32).
    // Process n in even/odd pairs so `par` is compile-time (rule #20) and the
    // t2 column (kcol = n>>1) load is shared by the pair (wave-broadcast read).
    #pragma unroll 1
    for (int nn = 0; nn < 16; ++nn) {
        const int n0 = w * 32 + nn * 2;
        const int kcol = n0 >> 1;
        float t2v[2][8];
        #pragma unroll
        for (int kt = 0; kt < 2; ++kt) {
            const float* p = &t2T2[kcol * PADZ + kt * 32 + lg * 8];
            #pragma unroll
            for (int e = 0; e < 8; ++e) t2v[kt][e] = p[e];
        }
        #pragma unroll
        for (int par = 0; par < 2; ++par) {
            const int n = n0 + par;
            // Build B fragments: T[z, col] = t2[k,z]*t3[l,z], hi + mid split.
            bf16x8 Bh[2], Bm[2];
            #pragma unroll
            for (int kt = 0; kt < 2; ++kt) {
                #pragma unroll
                for (int e = 0; e < 8; ++e) {
                    float pz = t2v[kt][e] * t3r[par][kt][e];
                    unsigned hb = bf16_rne_bits(pz);
                    float r = pz - __uint_as_float(hb);
                    Bh[kt][e] = (short)(hb >> 16);
                    Bm[kt][e] = (short)(__float_as_uint(r) >> 16);
                }
            }
            const int col = n * 16 + lr;
            #pragma unroll
            for (int m = 0; m < 4; ++m) {
                f32x4 acc = {0.f, 0.f, 0.f, 0.f};
                #pragma unroll
                for (int kt = 0; kt < 2; ++kt) {
                    acc = __builtin_amdgcn_mfma_f32_16x16x32_bf16(Ah[m][kt],   Bh[kt], acc, 0, 0, 0);
                    acc = __builtin_amdgcn_mfma_f32_16x16x32_bf16(Amid[m][kt], Bh[kt], acc, 0, 0, 0);
                    acc = __builtin_amdgcn_mfma_f32_16x16x32_bf16(Ah[m][kt],   Bm[kt], acc, 0, 0, 0);
                }
                const int jrow = m * 16 + lg * 4;
                #pragma unroll
                for (int r = 0; r < 4; ++r) {
                    op[(size_t)(jrow + r) * 2048 + col] = acc[r];
                }
            }
        }
    }
}

extern "C" void kernel_launch(void* const* d_in, const int* in_sizes, int n_in,
                              void* d_out, int out_size, void* d_ws, size_t ws_size,
                              hipStream_t stream) {
    const float* x1  = (const float*)d_in[0];
    const float* x2  = (const float*)d_in[1];
    const float* x3  = (const float*)d_in[2];
    const float* x4  = (const float*)d_in[3];
    const float* f   = (const float*)d_in[4];
    const float* Bm  = (const float*)d_in[5];
    const float* tW0 = (const float*)d_in[6];
    const float* tb0 = (const float*)d_in[7];
    const float* tW1 = (const float*)d_in[8];
    const float* tb1 = (const float*)d_in[9];
    const float* tW2 = (const float*)d_in[10];
    const float* tb2 = (const float*)d_in[11];
    const float* tW3 = (const float*)d_in[12];
    const float* tb3 = (const float*)d_in[13];
    const float* bW0 = (const float*)d_in[14];
    const float* bb0 = (const float*)d_in[15];
    const float* bW1 = (const float*)d_in[16];
    const float* bb1 = (const float*)d_in[17];
    const float* bW2 = (const float*)d_in[18];
    const float* bb2 = (const float*)d_in[19];
    const float* bW3 = (const float*)d_in[20];
    const float* bb3 = (const float*)d_in[21];

    float* ws  = (float*)d_ws;
    float* out = (float*)d_out;

    hipLaunchKernelGGL(net_eval, dim3(232), dim3(256), 0, stream,
                       x1, x2, x3, x4, f, Bm,
                       tW0, tb0, tW1, tb1, tW2, tb2, tW3, tb3,
                       bW0, bb0, bW1, bb1, bW2, bb2, bW3, bb3, ws);
    hipLaunchKernelGGL(cp_recon, dim3(512), dim3(256), 0, stream, ws, out);
}

// Round 5
// 361.691 us; speedup vs baseline: 1.0954x; 1.0011x over previous
//
#include <hip/hip_runtime.h>
#include <math.h>

// DeepOHeat_ST: 4 trunk MLPs + branch MLP, then rank-64 CP reconstruction
// out[b,i,j,k,l] = sum_z t0[i,z] t1[j,z] t2[k,z] t3[l,z] br[b,z]
//
// cp_recon v4 (MFMA, swapped operands): per block (b,i), the 64(j) x 2048(kl)
// plane is S(64x64) @ T(64x2048), T[z,kl] = t2[k,z]*t3[l,z], via
// mfma_f32_16x16x32_bf16 with 3-product bf16 split (hi=RNE, mid=trunc).
// v4 change vs v3: mfma(A=T-frag, B=S-frag) instead of (S,T). Round-4's PASS
// pins the HW positional maps (A-row lr -> m, B-col lr -> n, shared k-perm
// pi), so the swap provably yields D[m,n] = sum_z T[z, m] S[n, z], i.e. a
// lane's 4 acc regs are 4 CONSECUTIVE kl-columns of one j-row -> one float4
// store (4x fewer store instrs; epilogue was the remaining gap above the
// 43us output-write floor).
//
// ws layout (floats):
//   t0T [z][i]  (64x64)  @ 0
//   t1T [z][j]  (64x64)  @ 4096
//   t2T [z][k]  (64x64)  @ 8192
//   t3T [z][l]  (64x32)  @ 12288
//   brT [z][b]  (64x8)   @ 14336

#define HID 256
#define NFF 64

__global__ __launch_bounds__(256) void net_eval(
    const float* __restrict__ x1, const float* __restrict__ x2,
    const float* __restrict__ x3, const float* __restrict__ x4,
    const float* __restrict__ f,  const float* __restrict__ Bm,
    const float* __restrict__ tW0, const float* __restrict__ tb0,
    const float* __restrict__ tW1, const float* __restrict__ tb1,
    const float* __restrict__ tW2, const float* __restrict__ tb2,
    const float* __restrict__ tW3, const float* __restrict__ tb3,
    const float* __restrict__ bW0, const float* __restrict__ bb0,
    const float* __restrict__ bW1, const float* __restrict__ bb1,
    const float* __restrict__ bW2, const float* __restrict__ bb2,
    const float* __restrict__ bW3, const float* __restrict__ bb3,
    float* __restrict__ ws)
{
    __shared__ float bufA[HID];
    __shared__ float bufB[HID];
    const int t = threadIdx.x;
    const int bid = blockIdx.x;

    int net, row;
    if (bid < 192)      { net = bid >> 6; row = bid & 63; }
    else if (bid < 224) { net = 3;        row = bid - 192; }
    else                { net = 4;        row = bid - 224; }

    const float *W0, *B0v, *W1, *B1v, *W2, *B2v, *W3, *B3v;
    int in0;
    if (net < 4) {
        W0 = tW0 + (size_t)net * HID * 2 * NFF; B0v = tb0 + net * HID;
        W1 = tW1 + (size_t)net * HID * HID;     B1v = tb1 + net * HID;
        W2 = tW2 + (size_t)net * HID * HID;     B2v = tb2 + net * HID;
        W3 = tW3 + (size_t)net * 64 * HID;      B3v = tb3 + net * 64;
        in0 = 2 * NFF;
        const float* xp = (net == 0) ? x1 : (net == 1) ? x2 : (net == 2) ? x3 : x4;
        float xv = xp[row];
        if (t < 128) {
            float p = xv * Bm[t & 63];
            bufA[t] = (t < 64) ? cosf(p) : sinf(p);
        }
    } else {
        W0 = bW0; B0v = bb0; W1 = bW1; B1v = bb1;
        W2 = bW2; B2v = bb2; W3 = bW3; B3v = bb3;
        in0 = 256;
        bufA[t] = f[(size_t)row * 256 + t];
    }
    __syncthreads();

    // L0
    {
        const float4* wr = (const float4*)(W0 + (size_t)t * in0);
        const float4* iv = (const float4*)bufA;
        const int n4 = in0 >> 2;
        float4 a4 = make_float4(0.f, 0.f, 0.f, 0.f);
        for (int k = 0; k < n4; ++k) {
            float4 w = wr[k]; float4 v = iv[k];
            a4.x += w.x * v.x; a4.y += w.y * v.y;
            a4.z += w.z * v.z; a4.w += w.w * v.w;
        }
        float acc = B0v[t] + ((a4.x + a4.y) + (a4.z + a4.w));
        bufB[t] = acc / (1.0f + expf(-acc));
    }
    __syncthreads();

    // L1
    {
        const float4* wr = (const float4*)(W1 + (size_t)t * HID);
        const float4* iv = (const float4*)bufB;
        float4 a4 = make_float4(0.f, 0.f, 0.f, 0.f);
        for (int k = 0; k < HID / 4; ++k) {
            float4 w = wr[k]; float4 v = iv[k];
            a4.x += w.x * v.x; a4.y += w.y * v.y;
            a4.z += w.z * v.z; a4.w += w.w * v.w;
        }
        float acc = B1v[t] + ((a4.x + a4.y) + (a4.z + a4.w));
        bufA[t] = acc / (1.0f + expf(-acc));
    }
    __syncthreads();

    // L2
    {
        const float4* wr = (const float4*)(W2 + (size_t)t * HID);
        const float4* iv = (const float4*)bufA;
        float4 a4 = make_float4(0.f, 0.f, 0.f, 0.f);
        for (int k = 0; k < HID / 4; ++k) {
            float4 w = wr[k]; float4 v = iv[k];
            a4.x += w.x * v.x; a4.y += w.y * v.y;
            a4.z += w.z * v.z; a4.w += w.w * v.w;
        }
        float acc = B2v[t] + ((a4.x + a4.y) + (a4.z + a4.w));
        bufB[t] = acc / (1.0f + expf(-acc));
    }
    __syncthreads();

    // L3 -> transposed into ws
    if (t < 64) {
        const float4* wr = (const float4*)(W3 + (size_t)t * HID);
        const float4* iv = (const float4*)bufB;
        float4 a4 = make_float4(0.f, 0.f, 0.f, 0.f);
        for (int k = 0; k < HID / 4; ++k) {
            float4 w = wr[k]; float4 v = iv[k];
            a4.x += w.x * v.x; a4.y += w.y * v.y;
            a4.z += w.z * v.z; a4.w += w.w * v.w;
        }
        float acc = B3v[t] + ((a4.x + a4.y) + (a4.z + a4.w));
        int base, stride;
        if      (net == 0) { base = 0;     stride = 64; }
        else if (net == 1) { base = 4096;  stride = 64; }
        else if (net == 2) { base = 8192;  stride = 64; }
        else if (net == 3) { base = 12288; stride = 32; }
        else               { base = 14336; stride = 8;  }
        ws[base + t * stride + row] = acc;
    }
}

// ---------------- cp_recon v4: MFMA, swapped operands ----------------

#define PADZ 68   // f32 row stride for t2T2/t3T2 (64+4: 16B-aligned)
#define PADS 72   // ushort row stride for sHi/sMid (64+8: 16B-aligned)

typedef __attribute__((ext_vector_type(8))) short bf16x8;
typedef __attribute__((ext_vector_type(4))) float f32x4;

// RNE round f32 -> bf16, returned as the f32 bit pattern with low 16 zeroed
__device__ __forceinline__ unsigned bf16_rne_bits(float x) {
    unsigned u = __float_as_uint(x);
    return (u + 0x7fffu + ((u >> 16) & 1u)) & 0xffff0000u;
}

__global__ __launch_bounds__(256) void cp_recon(
    const float* __restrict__ ws, float* __restrict__ out)
{
    __shared__ __attribute__((aligned(16))) float t2T2[64 * PADZ];          // [k][z]
    __shared__ __attribute__((aligned(16))) float t3T2[32 * PADZ];          // [lv][z]
    __shared__ __attribute__((aligned(16))) unsigned short sHi [64 * PADS]; // [j][z]
    __shared__ __attribute__((aligned(16))) unsigned short sMid[64 * PADS];

    const int t = threadIdx.x;
    const int bid = blockIdx.x;
    const int b = bid >> 6;
    const int i = bid & 63;

    // stage t2 transposed to [k][z], t3 to [lv][z]
    #pragma unroll
    for (int m = 0; m < 16; ++m) {
        int idx = t + m * 256;            // = z*64 + k
        int z = idx >> 6, k = idx & 63;
        t2T2[k * PADZ + z] = ws[8192 + idx];
    }
    #pragma unroll
    for (int m = 0; m < 8; ++m) {
        int idx = t + m * 256;            // = z*32 + lv
        int z = idx >> 5, lv = idx & 31;
        t3T2[lv * PADZ + z] = ws[12288 + idx];
    }
    // S[j,z] = t0[i,z]*t1[j,z]*br[b,z], split hi (RNE) + mid (trunc)
    {
        const int j  = t & 63;
        const int zb = t >> 6;
        #pragma unroll
        for (int q = 0; q < 16; ++q) {
            int z = zb * 16 + q;
            float s = ws[z * 64 + i] * ws[4096 + z * 64 + j] * ws[14336 + z * 8 + b];
            unsigned hb = bf16_rne_bits(s);
            float r = s - __uint_as_float(hb);
            sHi [j * PADS + z] = (unsigned short)(hb >> 16);
            sMid[j * PADS + z] = (unsigned short)(__float_as_uint(r) >> 16);
        }
    }
    __syncthreads();

    const int w    = t >> 6;
    const int lane = t & 63;
    const int lg   = lane >> 4;   // k-group within fragment
    const int lr   = lane & 15;   // positional row/col index

    // Preload S fragments (hi & mid) for 4 j-tiles x 2 K-steps.
    bf16x8 Sh[4][2], Smid[4][2];
    #pragma unroll
    for (int m = 0; m < 4; ++m) {
        #pragma unroll
        for (int kt = 0; kt < 2; ++kt) {
            int j = m * 16 + lr, z0 = kt * 32 + lg * 8;
            Sh[m][kt]   = *(const bf16x8*)&sHi [j * PADS + z0];
            Smid[m][kt] = *(const bf16x8*)&sMid[j * PADS + z0];
        }
    }
    // Preload this lane's t3 rows (both n-parities): 16 z-values it needs.
    float t3r[2][2][8];
    #pragma unroll
    for (int par = 0; par < 2; ++par) {
        #pragma unroll
        for (int kt = 0; kt < 2; ++kt) {
            const float* p = &t3T2[(par * 16 + lr) * PADZ + kt * 32 + lg * 8];
            #pragma unroll
            for (int e = 0; e < 8; ++e) t3r[par][kt][e] = p[e];
        }
    }

    float* op = out + ((size_t)((b * 64 + i) * 64)) * 2048;  // j=0, col=0 base

    // Wave w owns cols [w*512, w*512+512) = N-tiles n in [w*32, w*32+32).
    // n processed in even/odd pairs: `par` compile-time, t2 column shared.
    #pragma unroll 1
    for (int nn = 0; nn < 16; ++nn) {
        const int n0 = w * 32 + nn * 2;
        const int kcol = n0 >> 1;
        float t2v[2][8];
        #pragma unroll
        for (int kt = 0; kt < 2; ++kt) {
            const float* p = &t2T2[kcol * PADZ + kt * 32 + lg * 8];
            #pragma unroll
            for (int e = 0; e < 8; ++e) t2v[kt][e] = p[e];
        }
        #pragma unroll
        for (int par = 0; par < 2; ++par) {
            const int n = n0 + par;
            // Build T fragments: T[z, col=n*16+lr] = t2[k,z]*t3[l,z], hi+mid.
            bf16x8 Th[2], Tm[2];
            #pragma unroll
            for (int kt = 0; kt < 2; ++kt) {
                #pragma unroll
                for (int e = 0; e < 8; ++e) {
                    float pz = t2v[kt][e] * t3r[par][kt][e];
                    unsigned hb = bf16_rne_bits(pz);
                    float r = pz - __uint_as_float(hb);
                    Th[kt][e] = (short)(hb >> 16);
                    Tm[kt][e] = (short)(__float_as_uint(r) >> 16);
                }
            }
            // Swapped operands: D[m,n'] = sum_z T[z, ncol(m)] * S[jrow(n'), z]
            // -> lane's 4 regs = 4 consecutive kl-cols at one j row.
            #pragma unroll
            for (int m = 0; m < 4; ++m) {
                f32x4 acc = {0.f, 0.f, 0.f, 0.f};
                #pragma unroll
                for (int kt = 0; kt < 2; ++kt) {
                    acc = __builtin_amdgcn_mfma_f32_16x16x32_bf16(Th[kt], Sh[m][kt],   acc, 0, 0, 0);
                    acc = __builtin_amdgcn_mfma_f32_16x16x32_bf16(Th[kt], Smid[m][kt], acc, 0, 0, 0);
                    acc = __builtin_amdgcn_mfma_f32_16x16x32_bf16(Tm[kt], Sh[m][kt],   acc, 0, 0, 0);
                }
                const int j = m * 16 + lr;
                const int colbase = n * 16 + lg * 4;
                *(float4*)&op[(size_t)j * 2048 + colbase] =
                    make_float4(acc[0], acc[1], acc[2], acc[3]);
            }
        }
    }
}

extern "C" void kernel_launch(void* const* d_in, const int* in_sizes, int n_in,
                              void* d_out, int out_size, void* d_ws, size_t ws_size,
                              hipStream_t stream) {
    const float* x1  = (const float*)d_in[0];
    const float* x2  = (const float*)d_in[1];
    const float* x3  = (const float*)d_in[2];
    const float* x4  = (const float*)d_in[3];
    const float* f   = (const float*)d_in[4];
    const float* Bm  = (const float*)d_in[5];
    const float* tW0 = (const float*)d_in[6];
    const float* tb0 = (const float*)d_in[7];
    const float* tW1 = (const float*)d_in[8];
    const float* tb1 = (const float*)d_in[9];
    const float* tW2 = (const float*)d_in[10];
    const float* tb2 = (const float*)d_in[11];
    const float* tW3 = (const float*)d_in[12];
    const float* tb3 = (const float*)d_in[13];
    const float* bW0 = (const float*)d_in[14];
    const float* bb0 = (const float*)d_in[15];
    const float* bW1 = (const float*)d_in[16];
    const float* bb1 = (const float*)d_in[17];
    const float* bW2 = (const float*)d_in[18];
    const float* bb2 = (const float*)d_in[19];
    const float* bW3 = (const float*)d_in[20];
    const float* bb3 = (const float*)d_in[21];

    float* ws  = (float*)d_ws;
    float* out = (float*)d_out;

    hipLaunchKernelGGL(net_eval, dim3(232), dim3(256), 0, stream,
                       x1, x2, x3, x4, f, Bm,
                       tW0, tb0, tW1, tb1, tW2, tb2, tW3, tb3,
                       bW0, bb0, bW1, bb1, bW2, bb2, bW3, bb3, ws);
    hipLaunchKernelGGL(cp_recon, dim3(512), dim3(256), 0, stream, ws, out);
}